// Round 19
// baseline (126.806 us; speedup 1.0000x reference)
//
#include <hip/hip_runtime.h>
#include <hip/hip_fp16.h>

#define Bb 4
#define Ss 1024
#define HID 1024
#define NH 16
#define NKV 8
#define HD 64

typedef _Float16 f16x8 __attribute__((ext_vector_type(8)));
typedef _Float16 f16x4 __attribute__((ext_vector_type(4)));
typedef float f32x4 __attribute__((ext_vector_type(4)));

typedef const __attribute__((address_space(1))) unsigned int gu32;
typedef __attribute__((address_space(3))) unsigned int lu32;

__device__ __forceinline__ void gl_lds16(const _Float16* g, _Float16* l) {
  __builtin_amdgcn_global_load_lds((gu32*)g, (lu32*)l, 16, 0, 0);
}

// ------------- fused fp32 -> fp16 conversion (all 5 tensors, one launch) ----
__global__ __launch_bounds__(256) void f2h_all(
    const float* __restrict__ a0, const float* __restrict__ a1,
    const float* __restrict__ a2, const float* __restrict__ a3,
    const float* __restrict__ a4, _Float16* __restrict__ o0,
    _Float16* __restrict__ o1, _Float16* __restrict__ o2,
    _Float16* __restrict__ o3, _Float16* __restrict__ o4) {
  const int bid = blockIdx.x;
  const float* src;
  _Float16* dst;
  int base;
  if (bid < 4096)      { src = a0; dst = o0; base = bid; }
  else if (bid < 5120) { src = a1; dst = o1; base = bid - 4096; }
  else if (bid < 5632) { src = a2; dst = o2; base = bid - 5120; }
  else if (bid < 6144) { src = a3; dst = o3; base = bid - 5632; }
  else                 { src = a4; dst = o4; base = bid - 6144; }
  const int i = base * 1024 + threadIdx.x * 4;
  const float4 v = *(const float4*)(src + i);
  f16x4 h;
  h[0] = (_Float16)v.x; h[1] = (_Float16)v.y;
  h[2] = (_Float16)v.z; h[3] = (_Float16)v.w;
  *(f16x4*)(dst + i) = h;
}

// ------------- QKV GEMM, BM=128 BN=64 BK=64, grid (32,32) = 4 blocks/CU ----
__global__ __launch_bounds__(256) void gemm_qkv(
    const _Float16* __restrict__ A, const _Float16* __restrict__ Bt,
    _Float16* __restrict__ qh, _Float16* __restrict__ kh,
    _Float16* __restrict__ vTp, const float* __restrict__ qnw,
    const float* __restrict__ knw, const float* __restrict__ cosd,
    const float* __restrict__ sind) {
  const int K = 1024;
  __shared__ __align__(16) _Float16 As[128 * 64];
  __shared__ __align__(16) _Float16 Bs[64 * 64];
  const int tid = threadIdx.x;
  const int wave = tid >> 6, lane = tid & 63;
  const int lr = lane & 15, lk = lane >> 4;
  const int bm = blockIdx.x * 128;
  const int by = blockIdx.y;       // 0..31 == head-slot hd2
  const int bn = by * 64;

  f32x4 acc[2][4] = {};

  const _Float16* asrc[4];
  const _Float16* bsrc[2];
  _Float16 *adst[4], *bdst[2];
#pragma unroll
  for (int i = 0; i < 4; ++i) {
    const int ch = i * 256 + tid;          // A: 1024 chunks (128 rows x 8)
    const int r = ch >> 3, ccl = ch & 7;
    const int ccg = ccl ^ (r & 7);
    asrc[i] = A + (size_t)(bm + r) * K + ccg * 8;
    adst[i] = As + ch * 8;
  }
#pragma unroll
  for (int i = 0; i < 2; ++i) {
    const int ch = i * 256 + tid;          // B: 512 chunks (64 rows x 8)
    const int r = ch >> 3, ccl = ch & 7;
    const int ccg = ccl ^ (r & 7);
    bsrc[i] = Bt + (size_t)(bn + r) * K + ccg * 8;
    bdst[i] = Bs + ch * 8;
  }

  for (int k0 = 0; k0 < K; k0 += 64) {
    __syncthreads();
#pragma unroll
    for (int i = 0; i < 4; ++i) gl_lds16(asrc[i] + k0, adst[i]);
#pragma unroll
    for (int i = 0; i < 2; ++i) gl_lds16(bsrc[i] + k0, bdst[i]);
    __syncthreads();
#pragma unroll
    for (int kk = 0; kk < 2; ++kk) {
      f16x8 af[2], bf[4];
#pragma unroll
      for (int m = 0; m < 2; ++m) {
        const int r = wave * 32 + m * 16 + lr;
        const int s = (kk * 4 + lk) ^ (r & 7);
        af[m] = *(const f16x8*)(As + r * 64 + s * 8);
      }
#pragma unroll
      for (int n = 0; n < 4; ++n) {
        const int r = n * 16 + lr;
        const int s = (kk * 4 + lk) ^ (r & 7);
        bf[n] = *(const f16x8*)(Bs + r * 64 + s * 8);
      }
#pragma unroll
      for (int m = 0; m < 2; ++m)
#pragma unroll
        for (int n = 0; n < 4; ++n)
          acc[m][n] =
              __builtin_amdgcn_mfma_f32_16x16x32_f16(af[m], bf[n], acc[m][n], 0, 0, 0);
    }
  }

  const int b = bm >> 10;
  const int s0 = bm & 1023;
  if (by < 24) {
    // Q (by<16) or K: fused RMSNorm(64) + RoPE, fp16 store
    const bool isQ = (by < 16);
    const float* nw = isQ ? qnw : knw;
    _Float16* dst = isQ ? qh : kh;
    const int ncols = isQ ? (NH * HD) : (NKV * HD);
    const int hcol = (isQ ? by : (by - 16)) * HD;
    float nwv[4];
#pragma unroll
    for (int n = 0; n < 4; ++n) nwv[n] = nw[n * 16 + lr];
#pragma unroll
    for (int m = 0; m < 2; ++m) {
#pragma unroll
      for (int j = 0; j < 4; ++j) {
        const int row = bm + wave * 32 + m * 16 + lk * 4 + j;
        float ss = 0.f;
#pragma unroll
        for (int n = 0; n < 4; ++n) ss += acc[m][n][j] * acc[m][n][j];
#pragma unroll
        for (int o = 1; o < 16; o <<= 1) ss += __shfl_xor(ss, o);
        const float rs = rsqrtf(ss * (1.0f / 64.0f) + 1e-6f);
        float y[4];
#pragma unroll
        for (int n = 0; n < 4; ++n) y[n] = acc[m][n][j] * rs * nwv[n];
        const size_t rb = (size_t)row * HD;
#pragma unroll
        for (int n = 0; n < 4; ++n) {
          const int d = n * 16 + lr;
          const float rot = (n < 2) ? -y[n + 2] : y[n - 2];
          dst[(size_t)row * ncols + hcol + d] =
              (_Float16)(y[n] * cosd[rb + d] + rot * sind[rb + d]);
        }
      }
    }
  } else {
    // V: fp16, stored TRANSPOSED: vT[((b*8+kv)*64+d)*S + s]
    const int kv = by - 24;
#pragma unroll
    for (int m = 0; m < 2; ++m) {
      const int sbase = s0 + wave * 32 + m * 16 + lk * 4;
#pragma unroll
      for (int n = 0; n < 4; ++n) {
        const int d = n * 16 + lr;
        f16x4 pk;
#pragma unroll
        for (int j = 0; j < 4; ++j) pk[j] = (_Float16)acc[m][n][j];
        *(f16x4*)&vTp[((size_t)((b * NKV + kv) * HD + d)) * Ss + sbase] = pk;
      }
    }
  }
}

// ------------- O-projection GEMM, BM=64 BN=64 BK=64 (grid 1024 = 4/CU) -----
// R18's TLP lever applied to O-proj: half the tile, double the resident
// blocks (2 -> 4 per CU). Wave owns 16 rows (acc[1][4], 8 MFMA/K-step);
// staging 4 chunks/thread (2xA + 2xB). A-panels re-read per N-block but
// A (8 MB fp16) is L2/L3-resident.
__global__ __launch_bounds__(256) void gemm_oproj(
    const _Float16* __restrict__ A, const _Float16* __restrict__ Bt,
    float* __restrict__ C, int N, int K) {
  __shared__ __align__(16) _Float16 As[64 * 64];
  __shared__ __align__(16) _Float16 Bs[64 * 64];
  const int tid = threadIdx.x;
  const int wave = tid >> 6, lane = tid & 63;
  const int lr = lane & 15, lk = lane >> 4;
  const int bm = blockIdx.x * 64;
  const int bn = blockIdx.y * 64;

  f32x4 acc[4] = {};

  const _Float16* asrc[2];
  const _Float16* bsrc[2];
  _Float16 *adst[2], *bdst[2];
#pragma unroll
  for (int i = 0; i < 2; ++i) {
    const int ch = i * 256 + tid;          // 512 chunks (64 rows x 8)
    const int r = ch >> 3, ccl = ch & 7;
    const int ccg = ccl ^ (r & 7);
    asrc[i] = A + (size_t)(bm + r) * K + ccg * 8;
    adst[i] = As + ch * 8;
    bsrc[i] = Bt + (size_t)(bn + r) * K + ccg * 8;
    bdst[i] = Bs + ch * 8;
  }

  for (int k0 = 0; k0 < K; k0 += 64) {
    __syncthreads();
#pragma unroll
    for (int i = 0; i < 2; ++i) {
      gl_lds16(asrc[i] + k0, adst[i]);
      gl_lds16(bsrc[i] + k0, bdst[i]);
    }
    __syncthreads();
#pragma unroll
    for (int kk = 0; kk < 2; ++kk) {
      const int ra = wave * 16 + lr;
      const int sa = (kk * 4 + lk) ^ (ra & 7);
      f16x8 af = *(const f16x8*)(As + ra * 64 + sa * 8);
      f16x8 bf[4];
#pragma unroll
      for (int n = 0; n < 4; ++n) {
        const int r = n * 16 + lr;
        const int s = (kk * 4 + lk) ^ (r & 7);
        bf[n] = *(const f16x8*)(Bs + r * 64 + s * 8);
      }
#pragma unroll
      for (int n = 0; n < 4; ++n)
        acc[n] = __builtin_amdgcn_mfma_f32_16x16x32_f16(af, bf[n], acc[n], 0, 0, 0);
    }
  }
  const int row = bm + wave * 16 + lk * 4;
#pragma unroll
  for (int n = 0; n < 4; ++n) {
    const int c = bn + n * 16 + lr;
#pragma unroll
    for (int j = 0; j < 4; ++j)
      C[(size_t)(row + j) * N + c] = acc[n][j];
  }
}

// ------------- MFMA flash attention, GQA head-merged ------------------------
// R16/R17 structure: 2 heads/block share staged K/V, qt remap, fixed softmax
// max (m=8, ||q||=||k||=8 after RMSNorm), exp2f, diag-only masking, coalesced
// weight stores, trailing zero tiles, coalesced ctx via Wh.
__global__ __launch_bounds__(512) void attn_kernel(
    const _Float16* __restrict__ qh, const _Float16* __restrict__ kh,
    const _Float16* __restrict__ vT, float* __restrict__ attn,
    _Float16* __restrict__ ctxh) {
  __shared__ __align__(16) _Float16 Ks[64][72];
  __shared__ __align__(16) _Float16 Vs[64][72];
  __shared__ __align__(16) _Float16 Wh[8][16][72];
  const int x = blockIdx.x, g = blockIdx.y, b = blockIdx.z;
  int qt;
  switch (b) {
    case 0:  qt = x; break;
    case 1:  qt = (x + 8) & 15; break;
    case 2:  qt = 15 - x; break;
    default: qt = (7 - x) & 15; break;
  }
  const int tid = threadIdx.x, wave = tid >> 6, lane = tid & 63;
  const int lr = lane & 15, lk = lane >> 4;
  const int h = 2 * g + (wave >> 2);      // this wave's head
  const int q0 = qt * 64, qrow0 = q0 + (wave & 3) * 16;
  float* attn_bh = attn + (size_t)(b * NH + h) * Ss * Ss;

  // staging: one 16B chunk per thread (64 rows x 8 chunks = 512 threads)
  const int sr = tid >> 3, sc = tid & 7;
  const _Float16* kb0 = kh + (size_t)(b * Ss) * (NKV * HD) + g * HD + sc * 8;
  const _Float16* vb0 = vT + (size_t)((b * NKV + g) * HD) * Ss + sc * 8;

  // Q A-fragments direct from global (once per block)
  const _Float16* qp = qh + (size_t)(b * Ss + qrow0 + lr) * (NH * HD) + h * HD + lk * 8;
  const f16x8 aq0 = *(const f16x8*)qp;
  const f16x8 aq1 = *(const f16x8*)(qp + 32);

  const float C1 = 0.18033688011112042f;  // 0.125 * log2(e)
  const float C2 = -11.541560327111707f;  // -8 * log2(e)

  // ---- pass A: softmax denominators only ----
  f16x8 pk = *(const f16x8*)(kb0 + (size_t)sr * (NKV * HD));
  float lsum[4] = {0.f, 0.f, 0.f, 0.f};
  for (int t = 0; t <= qt; ++t) {
    __syncthreads();  // previous tile's LDS reads done
    *(f16x8*)&Ks[sr][sc * 8] = pk;
    if (t < qt)
      pk = *(const f16x8*)(kb0 + (size_t)((t + 1) * 64 + sr) * (NKV * HD));
    __syncthreads();
    f32x4 acc[4] = {};
#pragma unroll
    for (int n = 0; n < 4; ++n) {
      f16x8 b0 = *(const f16x8*)&Ks[n * 16 + lr][lk * 8];
      acc[n] = __builtin_amdgcn_mfma_f32_16x16x32_f16(aq0, b0, acc[n], 0, 0, 0);
    }
#pragma unroll
    for (int n = 0; n < 4; ++n) {
      f16x8 b1 = *(const f16x8*)&Ks[n * 16 + lr][32 + lk * 8];
      acc[n] = __builtin_amdgcn_mfma_f32_16x16x32_f16(aq1, b1, acc[n], 0, 0, 0);
    }
    if (t < qt) {  // full tile: no mask
#pragma unroll
      for (int j = 0; j < 4; ++j)
#pragma unroll
        for (int n = 0; n < 4; ++n) lsum[j] += exp2f(fmaf(acc[n][j], C1, C2));
    } else {  // diagonal tile: the only masked one
#pragma unroll
      for (int j = 0; j < 4; ++j) {
        const int gr = qrow0 + lk * 4 + j;
#pragma unroll
        for (int n = 0; n < 4; ++n) {
          float p = exp2f(fmaf(acc[n][j], C1, C2));
          if (q0 + n * 16 + lr > gr) p = 0.f;
          lsum[j] += p;
        }
      }
    }
  }
  float linv[4];
#pragma unroll
  for (int j = 0; j < 4; ++j) {
#pragma unroll
    for (int o = 1; o < 16; o <<= 1) lsum[j] += __shfl_xor(lsum[j], o);
    linv[j] = 1.0f / lsum[j];
  }

  // ---- pass B: recompute scores, write weights once, PV accumulate ----
  pk = *(const f16x8*)(kb0 + (size_t)sr * (NKV * HD));
  f16x8 pv = *(const f16x8*)(vb0 + (size_t)sr * Ss);
  f32x4 acc2[4] = {};
  const int wr2 = lane >> 4;        // coalesced store: row subgroup 0..3
  const int wc2 = (lane & 15) * 4;  // 16B chunk, lanes 0..15 contiguous/row
  for (int t = 0; t <= qt; ++t) {
    __syncthreads();
    *(f16x8*)&Ks[sr][sc * 8] = pk;
    *(f16x8*)&Vs[sr][sc * 8] = pv;
    if (t < qt) {
      pk = *(const f16x8*)(kb0 + (size_t)((t + 1) * 64 + sr) * (NKV * HD));
      pv = *(const f16x8*)(vb0 + (size_t)sr * Ss + (t + 1) * 64);
    }
    __syncthreads();
    f32x4 acc[4] = {};
#pragma unroll
    for (int n = 0; n < 4; ++n) {
      f16x8 b0 = *(const f16x8*)&Ks[n * 16 + lr][lk * 8];
      acc[n] = __builtin_amdgcn_mfma_f32_16x16x32_f16(aq0, b0, acc[n], 0, 0, 0);
    }
#pragma unroll
    for (int n = 0; n < 4; ++n) {
      f16x8 b1 = *(const f16x8*)&Ks[n * 16 + lr][32 + lk * 8];
      acc[n] = __builtin_amdgcn_mfma_f32_16x16x32_f16(aq1, b1, acc[n], 0, 0, 0);
    }
    if (t < qt) {
#pragma unroll
      for (int j = 0; j < 4; ++j)
#pragma unroll
        for (int n = 0; n < 4; ++n) {
          const float w = exp2f(fmaf(acc[n][j], C1, C2)) * linv[j];
          Wh[wave][lk * 4 + j][n * 16 + lr] = (_Float16)w;
        }
    } else {
#pragma unroll
      for (int j = 0; j < 4; ++j) {
        const int gr = qrow0 + lk * 4 + j;
#pragma unroll
        for (int n = 0; n < 4; ++n) {
          float w = exp2f(fmaf(acc[n][j], C1, C2)) * linv[j];
          if (q0 + n * 16 + lr > gr) w = 0.f;
          Wh[wave][lk * 4 + j][n * 16 + lr] = (_Float16)w;
        }
      }
    }
    // PV: A = Wh rows (own 16 q-rows), B = V^T tile (in-wave DS ordering)
#pragma unroll
    for (int kc = 0; kc < 2; ++kc) {
      f16x8 aw = *(const f16x8*)&Wh[wave][lr][kc * 32 + lk * 8];
#pragma unroll
      for (int n = 0; n < 4; ++n) {
        f16x8 bv = *(const f16x8*)&Vs[n * 16 + lr][kc * 32 + lk * 8];
        acc2[n] = __builtin_amdgcn_mfma_f32_16x16x32_f16(aw, bv, acc2[n], 0, 0, 0);
      }
    }
    // weights -> HBM via Wh: fully-coalesced float4 stores
#pragma unroll
    for (int i2 = 0; i2 < 4; ++i2) {
      f16x4 hv = *(const f16x4*)&Wh[wave][wr2 + i2 * 4][wc2];
      *(float4*)&attn_bh[(size_t)(qrow0 + wr2 + i2 * 4) * Ss + t * 64 + wc2] =
          make_float4((float)hv[0], (float)hv[1], (float)hv[2], (float)hv[3]);
    }
  }

  // zero the fully-masked tiles (each half-block covers its own head)
  {
    float* attn_z = attn + (size_t)(b * NH + 2 * g + (tid >> 8)) * Ss * Ss;
    const int tz = tid & 255;
    for (int t = qt + 1; t < 16; ++t)
      for (int idx = tz; idx < 1024; idx += 256) {
        int r = idx >> 4, c4 = (idx & 15) * 4;
        *(float4*)&attn_z[(size_t)(q0 + r) * Ss + t * 64 + c4] =
            make_float4(0.f, 0.f, 0.f, 0.f);
      }
  }

  // ctx -> Wh (own wave section, in-wave DS ordering) -> coalesced f16x8
#pragma unroll
  for (int n = 0; n < 4; ++n)
#pragma unroll
    for (int j = 0; j < 4; ++j)
      Wh[wave][lk * 4 + j][n * 16 + lr] = (_Float16)acc2[n][j];
#pragma unroll
  for (int i = 0; i < 2; ++i) {
    const int cid = i * 64 + lane;   // 0..127 chunks (16 rows x 8)
    const int r3 = cid >> 3, c3 = cid & 7;
    f16x8 cv = *(const f16x8*)&Wh[wave][r3][c3 * 8];
    *(f16x8*)&ctxh[(size_t)(b * Ss + qrow0 + r3) * (NH * HD) + h * HD + c3 * 8] = cv;
  }
}

// ---------------- launch ----------------
extern "C" void kernel_launch(void* const* d_in, const int* in_sizes, int n_in,
                              void* d_out, int out_size, void* d_ws, size_t ws_size,
                              hipStream_t stream) {
  const float* hs   = (const float*)d_in[0];
  const float* cosb = (const float*)d_in[1];
  const float* sinb = (const float*)d_in[2];
  // d_in[3] attention_mask: causal, reproduced analytically
  const float* Wq = (const float*)d_in[4];
  const float* Wk = (const float*)d_in[5];
  const float* Wv = (const float*)d_in[6];
  const float* Wo = (const float*)d_in[7];
  const float* qw = (const float*)d_in[8];
  const float* kw = (const float*)d_in[9];

  char* ws = (char*)d_ws;
  _Float16* Xh    = (_Float16*)(ws);             // 4096x1024 fp16 (8 MB)
  _Float16* Wqkvh = (_Float16*)(ws + 8388608);   // 2048x1024 fp16 (4 MB) Q|K|V
  _Float16* Woh   = (_Float16*)(ws + 12582912);  // 1024x1024 fp16 (2 MB)
  _Float16* qh    = (_Float16*)(ws + 14680064);  // 4096x1024 fp16 (8 MB)
  _Float16* kh    = (_Float16*)(ws + 23068672);  // 4096x512  fp16 (4 MB)
  _Float16* vT    = (_Float16*)(ws + 27262976);  // [4*8*64][1024] (4 MB)
  _Float16* ctxh  = (_Float16*)(ws + 31457280);  // 4096x1024 fp16 (8 MB)

  float* out  = (float*)d_out;
  float* attn = out + (size_t)Bb * Ss * HID;

  f2h_all<<<7168, 256, 0, stream>>>(hs, Wq, Wk, Wv, Wo, Xh, Wqkvh,
                                    Wqkvh + 1048576, Wqkvh + 1572864, Woh);

  // fused QKV projection, 128x64 tiles -> 4 blocks/CU
  gemm_qkv<<<dim3(32, 32), 256, 0, stream>>>(Xh, Wqkvh, qh, kh, vT, qw, kw,
                                             cosb, sinb);

  // attention: GQA head-merged (2 heads/block share staged K/V), qt remap
  attn_kernel<<<dim3(16, 8, 4), 512, 0, stream>>>(qh, kh, vT, attn, ctxh);

  // O-projection, 64x64 tiles -> 4 blocks/CU (R18 TLP lever)
  gemm_oproj<<<dim3(64, 16), 256, 0, stream>>>(ctxh, Woh, out, 1024, 1024);
}

// Round 20
// 123.836 us; speedup vs baseline: 1.0240x; 1.0240x over previous
//
#include <hip/hip_runtime.h>
#include <hip/hip_fp16.h>

#define Bb 4
#define Ss 1024
#define HID 1024
#define NH 16
#define NKV 8
#define HD 64

typedef _Float16 f16x8 __attribute__((ext_vector_type(8)));
typedef _Float16 f16x4 __attribute__((ext_vector_type(4)));
typedef float f32x4 __attribute__((ext_vector_type(4)));

typedef const __attribute__((address_space(1))) unsigned int gu32;
typedef __attribute__((address_space(3))) unsigned int lu32;

__device__ __forceinline__ void gl_lds16(const _Float16* g, _Float16* l) {
  __builtin_amdgcn_global_load_lds((gu32*)g, (lu32*)l, 16, 0, 0);
}

// ------------- fused fp32 -> fp16 conversion (all 5 tensors, one launch) ----
__global__ __launch_bounds__(256) void f2h_all(
    const float* __restrict__ a0, const float* __restrict__ a1,
    const float* __restrict__ a2, const float* __restrict__ a3,
    const float* __restrict__ a4, _Float16* __restrict__ o0,
    _Float16* __restrict__ o1, _Float16* __restrict__ o2,
    _Float16* __restrict__ o3, _Float16* __restrict__ o4) {
  const int bid = blockIdx.x;
  const float* src;
  _Float16* dst;
  int base;
  if (bid < 4096)      { src = a0; dst = o0; base = bid; }
  else if (bid < 5120) { src = a1; dst = o1; base = bid - 4096; }
  else if (bid < 5632) { src = a2; dst = o2; base = bid - 5120; }
  else if (bid < 6144) { src = a3; dst = o3; base = bid - 5632; }
  else                 { src = a4; dst = o4; base = bid - 6144; }
  const int i = base * 1024 + threadIdx.x * 4;
  const float4 v = *(const float4*)(src + i);
  f16x4 h;
  h[0] = (_Float16)v.x; h[1] = (_Float16)v.y;
  h[2] = (_Float16)v.z; h[3] = (_Float16)v.w;
  *(f16x4*)(dst + i) = h;
}

// ------------- QKV GEMM, BM=128 BN=64 BK=64, grid (32,32) = 4 blocks/CU ----
__global__ __launch_bounds__(256) void gemm_qkv(
    const _Float16* __restrict__ A, const _Float16* __restrict__ Bt,
    _Float16* __restrict__ qh, _Float16* __restrict__ kh,
    _Float16* __restrict__ vTp, const float* __restrict__ qnw,
    const float* __restrict__ knw, const float* __restrict__ cosd,
    const float* __restrict__ sind) {
  const int K = 1024;
  __shared__ __align__(16) _Float16 As[128 * 64];
  __shared__ __align__(16) _Float16 Bs[64 * 64];
  const int tid = threadIdx.x;
  const int wave = tid >> 6, lane = tid & 63;
  const int lr = lane & 15, lk = lane >> 4;
  const int bm = blockIdx.x * 128;
  const int by = blockIdx.y;       // 0..31 == head-slot hd2
  const int bn = by * 64;

  f32x4 acc[2][4] = {};

  const _Float16* asrc[4];
  const _Float16* bsrc[2];
  _Float16 *adst[4], *bdst[2];
#pragma unroll
  for (int i = 0; i < 4; ++i) {
    const int ch = i * 256 + tid;          // A: 1024 chunks (128 rows x 8)
    const int r = ch >> 3, ccl = ch & 7;
    const int ccg = ccl ^ (r & 7);
    asrc[i] = A + (size_t)(bm + r) * K + ccg * 8;
    adst[i] = As + ch * 8;
  }
#pragma unroll
  for (int i = 0; i < 2; ++i) {
    const int ch = i * 256 + tid;          // B: 512 chunks (64 rows x 8)
    const int r = ch >> 3, ccl = ch & 7;
    const int ccg = ccl ^ (r & 7);
    bsrc[i] = Bt + (size_t)(bn + r) * K + ccg * 8;
    bdst[i] = Bs + ch * 8;
  }

  for (int k0 = 0; k0 < K; k0 += 64) {
    __syncthreads();
#pragma unroll
    for (int i = 0; i < 4; ++i) gl_lds16(asrc[i] + k0, adst[i]);
#pragma unroll
    for (int i = 0; i < 2; ++i) gl_lds16(bsrc[i] + k0, bdst[i]);
    __syncthreads();
#pragma unroll
    for (int kk = 0; kk < 2; ++kk) {
      f16x8 af[2], bf[4];
#pragma unroll
      for (int m = 0; m < 2; ++m) {
        const int r = wave * 32 + m * 16 + lr;
        const int s = (kk * 4 + lk) ^ (r & 7);
        af[m] = *(const f16x8*)(As + r * 64 + s * 8);
      }
#pragma unroll
      for (int n = 0; n < 4; ++n) {
        const int r = n * 16 + lr;
        const int s = (kk * 4 + lk) ^ (r & 7);
        bf[n] = *(const f16x8*)(Bs + r * 64 + s * 8);
      }
#pragma unroll
      for (int m = 0; m < 2; ++m)
#pragma unroll
        for (int n = 0; n < 4; ++n)
          acc[m][n] =
              __builtin_amdgcn_mfma_f32_16x16x32_f16(af[m], bf[n], acc[m][n], 0, 0, 0);
    }
  }

  const int b = bm >> 10;
  const int s0 = bm & 1023;
  if (by < 24) {
    // Q (by<16) or K: fused RMSNorm(64) + RoPE, fp16 store
    const bool isQ = (by < 16);
    const float* nw = isQ ? qnw : knw;
    _Float16* dst = isQ ? qh : kh;
    const int ncols = isQ ? (NH * HD) : (NKV * HD);
    const int hcol = (isQ ? by : (by - 16)) * HD;
    float nwv[4];
#pragma unroll
    for (int n = 0; n < 4; ++n) nwv[n] = nw[n * 16 + lr];
#pragma unroll
    for (int m = 0; m < 2; ++m) {
#pragma unroll
      for (int j = 0; j < 4; ++j) {
        const int row = bm + wave * 32 + m * 16 + lk * 4 + j;
        float ss = 0.f;
#pragma unroll
        for (int n = 0; n < 4; ++n) ss += acc[m][n][j] * acc[m][n][j];
#pragma unroll
        for (int o = 1; o < 16; o <<= 1) ss += __shfl_xor(ss, o);
        const float rs = rsqrtf(ss * (1.0f / 64.0f) + 1e-6f);
        float y[4];
#pragma unroll
        for (int n = 0; n < 4; ++n) y[n] = acc[m][n][j] * rs * nwv[n];
        const size_t rb = (size_t)row * HD;
#pragma unroll
        for (int n = 0; n < 4; ++n) {
          const int d = n * 16 + lr;
          const float rot = (n < 2) ? -y[n + 2] : y[n - 2];
          dst[(size_t)row * ncols + hcol + d] =
              (_Float16)(y[n] * cosd[rb + d] + rot * sind[rb + d]);
        }
      }
    }
  } else {
    // V: fp16, stored TRANSPOSED: vT[((b*8+kv)*64+d)*S + s]
    const int kv = by - 24;
#pragma unroll
    for (int m = 0; m < 2; ++m) {
      const int sbase = s0 + wave * 32 + m * 16 + lk * 4;
#pragma unroll
      for (int n = 0; n < 4; ++n) {
        const int d = n * 16 + lr;
        f16x4 pk;
#pragma unroll
        for (int j = 0; j < 4; ++j) pk[j] = (_Float16)acc[m][n][j];
        *(f16x4*)&vTp[((size_t)((b * NKV + kv) * HD + d)) * Ss + sbase] = pk;
      }
    }
  }
}

// ------------- O-projection GEMM, BM=128 BN=64 BK=64 (R18 proven config) ---
__global__ __launch_bounds__(256) void gemm_oproj(
    const _Float16* __restrict__ A, const _Float16* __restrict__ Bt,
    float* __restrict__ C, int N, int K) {
  __shared__ __align__(16) _Float16 As[128][64];
  __shared__ __align__(16) _Float16 Bs[64][64];
  const int tid = threadIdx.x;
  const int wave = tid >> 6, lane = tid & 63;
  const int lr = lane & 15, lk = lane >> 4;
  const int bm = blockIdx.x * 128;
  const int bn = blockIdx.y * 64;

  f32x4 acc[2][4] = {};

  const _Float16* asrc[4];
  const _Float16* bsrc[2];
  _Float16 *adst[4], *bdst[2];
#pragma unroll
  for (int i = 0; i < 4; ++i) {
    const int ch = i * 256 + tid;
    const int r = ch >> 3, ccl = ch & 7;
    const int ccg = ccl ^ (r & 7);
    asrc[i] = A + (size_t)(bm + r) * K + ccg * 8;
    adst[i] = &As[0][0] + ch * 8;
  }
#pragma unroll
  for (int i = 0; i < 2; ++i) {
    const int ch = i * 256 + tid;          // 0..511
    const int r = ch >> 3, ccl = ch & 7;
    const int ccg = ccl ^ (r & 7);
    bsrc[i] = Bt + (size_t)(bn + r) * K + ccg * 8;
    bdst[i] = &Bs[0][0] + ch * 8;
  }

  for (int k0 = 0; k0 < K; k0 += 64) {
    __syncthreads();
#pragma unroll
    for (int i = 0; i < 4; ++i) gl_lds16(asrc[i] + k0, adst[i]);
#pragma unroll
    for (int i = 0; i < 2; ++i) gl_lds16(bsrc[i] + k0, bdst[i]);
    __syncthreads();
#pragma unroll
    for (int kk = 0; kk < 2; ++kk) {
      f16x8 af[2], bf[4];
#pragma unroll
      for (int m = 0; m < 2; ++m) {
        const int r = wave * 32 + m * 16 + lr;
        const int s = (kk * 4 + lk) ^ (r & 7);
        af[m] = *(const f16x8*)(&As[r][0] + s * 8);
      }
#pragma unroll
      for (int n = 0; n < 4; ++n) {
        const int r = n * 16 + lr;
        const int s = (kk * 4 + lk) ^ (r & 7);
        bf[n] = *(const f16x8*)(&Bs[r][0] + s * 8);
      }
#pragma unroll
      for (int m = 0; m < 2; ++m)
#pragma unroll
        for (int n = 0; n < 4; ++n)
          acc[m][n] =
              __builtin_amdgcn_mfma_f32_16x16x32_f16(af[m], bf[n], acc[m][n], 0, 0, 0);
    }
  }
#pragma unroll
  for (int m = 0; m < 2; ++m) {
    const int row = bm + wave * 32 + m * 16 + lk * 4;
#pragma unroll
    for (int n = 0; n < 4; ++n) {
      const int c = bn + n * 16 + lr;
#pragma unroll
      for (int j = 0; j < 4; ++j)
        C[(size_t)(row + j) * N + c] = acc[m][n][j];
    }
  }
}

// ------------- MFMA flash attention, GQA head-merged ------------------------
// R16/R18 best-known: 2 heads/block share staged K/V, qt remap, fixed softmax
// max (m=8, ||q||=||k||=8 after RMSNorm), exp2f, diag-only masking, coalesced
// weight stores, trailing zero tiles, coalesced ctx via Wh.
__global__ __launch_bounds__(512) void attn_kernel(
    const _Float16* __restrict__ qh, const _Float16* __restrict__ kh,
    const _Float16* __restrict__ vT, float* __restrict__ attn,
    _Float16* __restrict__ ctxh) {
  __shared__ __align__(16) _Float16 Ks[64][72];
  __shared__ __align__(16) _Float16 Vs[64][72];
  __shared__ __align__(16) _Float16 Wh[8][16][72];
  const int x = blockIdx.x, g = blockIdx.y, b = blockIdx.z;
  int qt;
  switch (b) {
    case 0:  qt = x; break;
    case 1:  qt = (x + 8) & 15; break;
    case 2:  qt = 15 - x; break;
    default: qt = (7 - x) & 15; break;
  }
  const int tid = threadIdx.x, wave = tid >> 6, lane = tid & 63;
  const int lr = lane & 15, lk = lane >> 4;
  const int h = 2 * g + (wave >> 2);      // this wave's head
  const int q0 = qt * 64, qrow0 = q0 + (wave & 3) * 16;
  float* attn_bh = attn + (size_t)(b * NH + h) * Ss * Ss;

  // staging: one 16B chunk per thread (64 rows x 8 chunks = 512 threads)
  const int sr = tid >> 3, sc = tid & 7;
  const _Float16* kb0 = kh + (size_t)(b * Ss) * (NKV * HD) + g * HD + sc * 8;
  const _Float16* vb0 = vT + (size_t)((b * NKV + g) * HD) * Ss + sc * 8;

  // Q A-fragments direct from global (once per block)
  const _Float16* qp = qh + (size_t)(b * Ss + qrow0 + lr) * (NH * HD) + h * HD + lk * 8;
  const f16x8 aq0 = *(const f16x8*)qp;
  const f16x8 aq1 = *(const f16x8*)(qp + 32);

  const float C1 = 0.18033688011112042f;  // 0.125 * log2(e)
  const float C2 = -11.541560327111707f;  // -8 * log2(e)

  // ---- pass A: softmax denominators only ----
  f16x8 pk = *(const f16x8*)(kb0 + (size_t)sr * (NKV * HD));
  float lsum[4] = {0.f, 0.f, 0.f, 0.f};
  for (int t = 0; t <= qt; ++t) {
    __syncthreads();  // previous tile's LDS reads done
    *(f16x8*)&Ks[sr][sc * 8] = pk;
    if (t < qt)
      pk = *(const f16x8*)(kb0 + (size_t)((t + 1) * 64 + sr) * (NKV * HD));
    __syncthreads();
    f32x4 acc[4] = {};
#pragma unroll
    for (int n = 0; n < 4; ++n) {
      f16x8 b0 = *(const f16x8*)&Ks[n * 16 + lr][lk * 8];
      acc[n] = __builtin_amdgcn_mfma_f32_16x16x32_f16(aq0, b0, acc[n], 0, 0, 0);
    }
#pragma unroll
    for (int n = 0; n < 4; ++n) {
      f16x8 b1 = *(const f16x8*)&Ks[n * 16 + lr][32 + lk * 8];
      acc[n] = __builtin_amdgcn_mfma_f32_16x16x32_f16(aq1, b1, acc[n], 0, 0, 0);
    }
    if (t < qt) {  // full tile: no mask
#pragma unroll
      for (int j = 0; j < 4; ++j)
#pragma unroll
        for (int n = 0; n < 4; ++n) lsum[j] += exp2f(fmaf(acc[n][j], C1, C2));
    } else {  // diagonal tile: the only masked one
#pragma unroll
      for (int j = 0; j < 4; ++j) {
        const int gr = qrow0 + lk * 4 + j;
#pragma unroll
        for (int n = 0; n < 4; ++n) {
          float p = exp2f(fmaf(acc[n][j], C1, C2));
          if (q0 + n * 16 + lr > gr) p = 0.f;
          lsum[j] += p;
        }
      }
    }
  }
  float linv[4];
#pragma unroll
  for (int j = 0; j < 4; ++j) {
#pragma unroll
    for (int o = 1; o < 16; o <<= 1) lsum[j] += __shfl_xor(lsum[j], o);
    linv[j] = 1.0f / lsum[j];
  }

  // ---- pass B: recompute scores, write weights once, PV accumulate ----
  pk = *(const f16x8*)(kb0 + (size_t)sr * (NKV * HD));
  f16x8 pv = *(const f16x8*)(vb0 + (size_t)sr * Ss);
  f32x4 acc2[4] = {};
  const int wr2 = lane >> 4;        // coalesced store: row subgroup 0..3
  const int wc2 = (lane & 15) * 4;  // 16B chunk, lanes 0..15 contiguous/row
  for (int t = 0; t <= qt; ++t) {
    __syncthreads();
    *(f16x8*)&Ks[sr][sc * 8] = pk;
    *(f16x8*)&Vs[sr][sc * 8] = pv;
    if (t < qt) {
      pk = *(const f16x8*)(kb0 + (size_t)((t + 1) * 64 + sr) * (NKV * HD));
      pv = *(const f16x8*)(vb0 + (size_t)sr * Ss + (t + 1) * 64);
    }
    __syncthreads();
    f32x4 acc[4] = {};
#pragma unroll
    for (int n = 0; n < 4; ++n) {
      f16x8 b0 = *(const f16x8*)&Ks[n * 16 + lr][lk * 8];
      acc[n] = __builtin_amdgcn_mfma_f32_16x16x32_f16(aq0, b0, acc[n], 0, 0, 0);
    }
#pragma unroll
    for (int n = 0; n < 4; ++n) {
      f16x8 b1 = *(const f16x8*)&Ks[n * 16 + lr][32 + lk * 8];
      acc[n] = __builtin_amdgcn_mfma_f32_16x16x32_f16(aq1, b1, acc[n], 0, 0, 0);
    }
    if (t < qt) {
#pragma unroll
      for (int j = 0; j < 4; ++j)
#pragma unroll
        for (int n = 0; n < 4; ++n) {
          const float w = exp2f(fmaf(acc[n][j], C1, C2)) * linv[j];
          Wh[wave][lk * 4 + j][n * 16 + lr] = (_Float16)w;
        }
    } else {
#pragma unroll
      for (int j = 0; j < 4; ++j) {
        const int gr = qrow0 + lk * 4 + j;
#pragma unroll
        for (int n = 0; n < 4; ++n) {
          float w = exp2f(fmaf(acc[n][j], C1, C2)) * linv[j];
          if (q0 + n * 16 + lr > gr) w = 0.f;
          Wh[wave][lk * 4 + j][n * 16 + lr] = (_Float16)w;
        }
      }
    }
    // PV: A = Wh rows (own 16 q-rows), B = V^T tile (in-wave DS ordering)
#pragma unroll
    for (int kc = 0; kc < 2; ++kc) {
      f16x8 aw = *(const f16x8*)&Wh[wave][lr][kc * 32 + lk * 8];
#pragma unroll
      for (int n = 0; n < 4; ++n) {
        f16x8 bv = *(const f16x8*)&Vs[n * 16 + lr][kc * 32 + lk * 8];
        acc2[n] = __builtin_amdgcn_mfma_f32_16x16x32_f16(aw, bv, acc2[n], 0, 0, 0);
      }
    }
    // weights -> HBM via Wh: fully-coalesced float4 stores
#pragma unroll
    for (int i2 = 0; i2 < 4; ++i2) {
      f16x4 hv = *(const f16x4*)&Wh[wave][wr2 + i2 * 4][wc2];
      *(float4*)&attn_bh[(size_t)(qrow0 + wr2 + i2 * 4) * Ss + t * 64 + wc2] =
          make_float4((float)hv[0], (float)hv[1], (float)hv[2], (float)hv[3]);
    }
  }

  // zero the fully-masked tiles (each half-block covers its own head)
  {
    float* attn_z = attn + (size_t)(b * NH + 2 * g + (tid >> 8)) * Ss * Ss;
    const int tz = tid & 255;
    for (int t = qt + 1; t < 16; ++t)
      for (int idx = tz; idx < 1024; idx += 256) {
        int r = idx >> 4, c4 = (idx & 15) * 4;
        *(float4*)&attn_z[(size_t)(q0 + r) * Ss + t * 64 + c4] =
            make_float4(0.f, 0.f, 0.f, 0.f);
      }
  }

  // ctx -> Wh (own wave section, in-wave DS ordering) -> coalesced f16x8
#pragma unroll
  for (int n = 0; n < 4; ++n)
#pragma unroll
    for (int j = 0; j < 4; ++j)
      Wh[wave][lk * 4 + j][n * 16 + lr] = (_Float16)acc2[n][j];
#pragma unroll
  for (int i = 0; i < 2; ++i) {
    const int cid = i * 64 + lane;   // 0..127 chunks (16 rows x 8)
    const int r3 = cid >> 3, c3 = cid & 7;
    f16x8 cv = *(const f16x8*)&Wh[wave][r3][c3 * 8];
    *(f16x8*)&ctxh[(size_t)(b * Ss + qrow0 + r3) * (NH * HD) + h * HD + c3 * 8] = cv;
  }
}

// ---------------- launch ----------------
extern "C" void kernel_launch(void* const* d_in, const int* in_sizes, int n_in,
                              void* d_out, int out_size, void* d_ws, size_t ws_size,
                              hipStream_t stream) {
  const float* hs   = (const float*)d_in[0];
  const float* cosb = (const float*)d_in[1];
  const float* sinb = (const float*)d_in[2];
  // d_in[3] attention_mask: causal, reproduced analytically
  const float* Wq = (const float*)d_in[4];
  const float* Wk = (const float*)d_in[5];
  const float* Wv = (const float*)d_in[6];
  const float* Wo = (const float*)d_in[7];
  const float* qw = (const float*)d_in[8];
  const float* kw = (const float*)d_in[9];

  char* ws = (char*)d_ws;
  _Float16* Xh    = (_Float16*)(ws);             // 4096x1024 fp16 (8 MB)
  _Float16* Wqkvh = (_Float16*)(ws + 8388608);   // 2048x1024 fp16 (4 MB) Q|K|V
  _Float16* Woh   = (_Float16*)(ws + 12582912);  // 1024x1024 fp16 (2 MB)
  _Float16* qh    = (_Float16*)(ws + 14680064);  // 4096x1024 fp16 (8 MB)
  _Float16* kh    = (_Float16*)(ws + 23068672);  // 4096x512  fp16 (4 MB)
  _Float16* vT    = (_Float16*)(ws + 27262976);  // [4*8*64][1024] (4 MB)
  _Float16* ctxh  = (_Float16*)(ws + 31457280);  // 4096x1024 fp16 (8 MB)

  float* out  = (float*)d_out;
  float* attn = out + (size_t)Bb * Ss * HID;

  f2h_all<<<7168, 256, 0, stream>>>(hs, Wq, Wk, Wv, Wo, Xh, Wqkvh,
                                    Wqkvh + 1048576, Wqkvh + 1572864, Woh);

  // fused QKV projection, 128x64 tiles -> 4 blocks/CU
  gemm_qkv<<<dim3(32, 32), 256, 0, stream>>>(Xh, Wqkvh, qh, kh, vT, qw, kw,
                                             cosb, sinb);

  // attention: GQA head-merged (2 heads/block share staged K/V), qt remap
  attn_kernel<<<dim3(16, 8, 4), 512, 0, stream>>>(qh, kh, vT, attn, ctxh);

  // O-projection, 128x64 tiles (R18 proven config)
  gemm_oproj<<<dim3(32, 16), 256, 0, stream>>>(ctxh, Woh, out, 1024, 1024);
}